// Round 11
// baseline (303.168 us; speedup 1.0000x reference)
//
#include <hip/hip_runtime.h>
#include <math.h>

typedef __bf16 bf16;
typedef __bf16 bf16x8 __attribute__((ext_vector_type(8)));
typedef unsigned short u16;
typedef unsigned short u16x8 __attribute__((ext_vector_type(8)));
typedef float f32x4 __attribute__((ext_vector_type(4)));
typedef float f32x16 __attribute__((ext_vector_type(16)));
typedef unsigned int u32x4 __attribute__((ext_vector_type(4)));

__device__ __forceinline__ void load_lds16(const void* g, void* l) {
    __builtin_amdgcn_global_load_lds(
        (const __attribute__((address_space(1))) unsigned int*)g,
        (__attribute__((address_space(3))) unsigned int*)l, 16, 0, 0);
}

// ---------------------------------------------------------------------------
// prep_w2: W2 [cout][ci][tap] f32 -> B-frag buffer for mfma_32x32x16 (conv2),
// PLUS W1 [32][9] f32 -> B-frag buffer w1f for conv1 (K=16, taps 9..15 = 0).
// ---------------------------------------------------------------------------
__global__ void prep_w2(const float* __restrict__ W2, bf16* __restrict__ w2r,
                        const float* __restrict__ W1, bf16* __restrict__ w1f) {
    int e = blockIdx.x * 256 + threadIdx.x;
    if (e < 18432) {
        int j  = e & 7;
        int l  = (e >> 3) & 63;
        int f  = e >> 9;
        int s  = f >> 1;
        int nt = f & 1;
        int tap  = s >> 1;
        int ci   = (s & 1) * 16 + (l >> 5) * 8 + j;
        int cout = nt * 32 + (l & 31);
        w2r[e] = (bf16)W2[cout * 288 + ci * 9 + tap];
    } else {
        int e2 = e - 18432;
        if (e2 < 512) {
            int j = e2 & 7;
            int l = e2 >> 3;
            int k = (l >> 5) * 8 + j;       // tap index (K)
            int n = l & 31;                 // cout
            w1f[e2] = (k < 9) ? (bf16)W1[n * 9 + k] : (bf16)0.f;
        }
    }
}

// ---------------------------------------------------------------------------
// prep_wl1t: Wl1 f32 [12544][128] -> bf16 [128][12544] with permuted K:
// wl1t[n][k'] where k' = site*64 + cout  <->  Wl1 row k = cout*196 + site.
// ---------------------------------------------------------------------------
__global__ void prep_wl1t(const float* __restrict__ Wl1, bf16* __restrict__ wl1t) {
    __shared__ float tile[32 * 129];
    const int t  = threadIdx.x;
    const int s  = blockIdx.x;      // site 0..195
    const int cg = blockIdx.y;      // cout half
    for (int e = t; e < 4096; e += 256) {
        int cl = e >> 7, n = e & 127;
        tile[cl * 129 + n] = Wl1[((long)(cg * 32 + cl) * 196 + s) * 128 + n];
    }
    __syncthreads();
    for (int e = t; e < 4096; e += 256) {
        int n = e >> 5, cl = e & 31;
        wl1t[(long)n * 12544 + s * 64 + cg * 32 + cl] = (bf16)tile[cl * 129 + n];
    }
}

// ---------------------------------------------------------------------------
// conv_fused: BOTH convs on MFMA. R11: h1s re-layout [row][col*32ci] with
// row stride 1032 el (8-el pad -> +4 bank/row) and col swizzle ((col&6)<<2)
// applied to the ci-block. Tap offsets become ds_read IMMEDIATES
// (dr*2064 B); only 6 base addrs per Mt (3 dc x 2 ci-halves). Phase 2 writes
// every h1s cell (mask handles halo) -> no zero-init pass. p = row*32+col.
// __launch_bounds__(256,3) REQUIRED: (256,4) spills breg (R3, R6: 1.3 GB
// scratch). DO NOT raise to 4.  !! LDS fills > 256 elems: strided loops (R8).
// ---------------------------------------------------------------------------
__global__ __launch_bounds__(256, 3)
void conv_fused(const float* __restrict__ x, const float* __restrict__ b1,
                const bf16* __restrict__ w2r, const bf16* __restrict__ w1f,
                const float* __restrict__ b2, bf16* __restrict__ pooled)
{
    __shared__ __attribute__((aligned(16))) bf16  h1s[16 * 1032];   // 33024 B
    __shared__ __attribute__((aligned(16))) bf16  Aim[512 * 16];    // 16384 B
    __shared__ __attribute__((aligned(16))) float mrow[512];        //  2048 B
    __shared__ __attribute__((aligned(16))) float mneg[98 * 4];     //  1568 B
    __shared__ __attribute__((aligned(16))) bf16  xs[640];          //  1280 B

    const int t    = threadIdx.x;
    const int lane = t & 63;
    const int wv   = t >> 6;
    const int img  = blockIdx.x >> 1;
    const int hb   = blockIdx.x & 1;        // image half
    const int nt   = wv & 1;                // conv2 cout half
    const int wp   = wv >> 1;               // conv2 Mt parity
    const int ml31 = lane & 31;
    const int lg   = lane >> 5;

    const float* xi = x + img * 784;

    // global loads early (L2-resident; latency hides behind staging)
    bf16x8 breg[18];
    {
        const bf16x8* wp2 = (const bf16x8*)w2r;
        #pragma unroll
        for (int s = 0; s < 18; s++)
            breg[s] = wp2[(2 * s + nt) * 64 + lane];
    }
    const bf16x8 w1frag = *(const bf16x8*)&w1f[lane * 8];
    const float  b1r    = b1[ml31];
    const float  bias2  = b2[nt * 32 + ml31];

    // stage x tile (bf16): xs[j*32+c] = x[hb*14-2+j][c-1], rows 0..19 (pad)
    for (int e = t; e < 640; e += 256) {
        int j  = e >> 5;
        int c  = e & 31;
        int xr = hb * 14 - 2 + j;
        int xc = c - 1;
        float v = 0.f;
        if (xr >= 0 && xr < 28 && xc >= 0 && xc < 28) v = xi[xr * 28 + xc];
        xs[e] = (bf16)v;
    }
    __syncthreads();

    // ---- phase 1: im2col (512 pos = 16 rows x 32 cols) + masks (u16 copies)
    const u16* xu = (const u16*)xs;
    #pragma unroll
    for (int pp = 0; pp < 2; pp++) {
        int p = t + pp * 256;               // 0..511
        int r = p >> 5, c = p & 31;
        int b = r * 32 + c - 1;             // c=0 -> reads pad (masked)
        u16 v0 = xu[b],      v1 = xu[b + 1],  v2 = xu[b + 2];
        u16 v3 = xu[b + 32], v4 = xu[b + 33], v5 = xu[b + 34];
        u16 v6 = xu[b + 64], v7 = xu[b + 65], v8 = xu[b + 66];
        u16x8 t0;
        t0[0] = v0; t0[1] = v1; t0[2] = v2; t0[3] = v3;
        t0[4] = v4; t0[5] = v5; t0[6] = v6; t0[7] = v7;
        u16x8 t1;
        #pragma unroll
        for (int j = 0; j < 8; j++) t1[j] = 0;
        t1[0] = v8;
        *(u16x8*)&Aim[p * 16]     = *(u16x8*)&t0;
        *(u16x8*)&Aim[p * 16 + 8] = *(u16x8*)&t1;
        // center valid: col in [1,28] and x-center nonzero (row-validity is
        // implicit: out-of-image rows staged as 0)
        mrow[p] = (c >= 1 && c <= 28 && (v4 & 0x7fff) != 0) ? 1.f : 0.f;
    }
    // mneg: 392 entries > 256 threads -> strided loop (R8 lesson)
    for (int e = t; e < 392; e += 256) {
        int s   = e >> 2, q = e & 3;
        int spi = s / 14, spj = s - spi * 14;
        u16 cv = xu[(2 * spi + (q >> 1) + 2) * 32 + 2 * spj + (q & 1) + 1];
        mneg[e] = ((cv & 0x7fff) != 0) ? 0.f : -1e30f;
    }
    __syncthreads();

    // ---- phase 2: conv1 via MFMA 32x32x16; 16 M-tiles, 4 per wave.
    // Writes EVERY h1s cell (mask zeroes halo cols 0,29,30,31).
    for (int Mt = wv; Mt < 16; Mt += 4) {
        int m = Mt * 32 + ml31;
        bf16x8 af = *(const bf16x8*)&Aim[m * 16 + lg * 8];
        f32x16 acc;
        #pragma unroll
        for (int e = 0; e < 16; e++) acc[e] = b1r;
        acc = __builtin_amdgcn_mfma_f32_32x32x16_bf16(af, w1frag, acc, 0, 0, 0);
        const int rowb = Mt * 1032;                  // row == Mt (p = Mt*32+off)
        #pragma unroll
        for (int run = 0; run < 4; run++) {
            int p0 = Mt * 32 + run * 8 + 4 * lg;
            f32x4 mk = *(const f32x4*)&mrow[p0];
            #pragma unroll
            for (int j = 0; j < 4; j++) {
                float s = acc[run * 4 + j];
                float o = (mk[j] != 0.f) ? fmaxf(s, 0.f) : 0.f;  // select: NaN-safe
                int col = run * 8 + 4 * lg + j;
                int swz = (col & 6) << 2;
                h1s[rowb + col * 32 + (ml31 ^ swz)] = (bf16)o;
            }
        }
    }
    __syncthreads();    // h1s ready

    // ---- phase 3: conv2 Mt loop (13 tiles of 32 M-rows, 98 pooled sites)
    const int half = lg;
    const int cib  = half * 8;

    int q  = ml31 & 3;
    int pj = wp * 8 + (ml31 >> 2);
    int pi = 0;
    if (pj >= 14) { pj -= 14; pi = 1; }

    bf16* pout = pooled + (long)img * 12544 + hb * 98 * 64 + nt * 32 + ml31;

    for (int Mt = wp; Mt < 13; Mt += 2) {
        int row = 2 * pi + (q >> 1);
        if (row > 13) row = 13;             // keep reads (row+2) in bounds;
                                            // affected lanes' stores guarded
        int colb = 2 * pj + (q & 1);
        int rowb = row * 1032;

        // 6 base addresses; tap row-offsets are ds_read immediates (dr*1032 el)
        int e0a[3], e1a[3];
        #pragma unroll
        for (int dc = 0; dc < 3; dc++) {
            int cc   = colb + dc;
            int swz  = (cc & 6) << 2;
            int base = rowb + cc * 32;
            e0a[dc] = base + (cib ^ swz);
            e1a[dc] = base + ((16 + cib) ^ swz);
        }

        f32x16 accA, accB = {};
        #pragma unroll
        for (int e = 0; e < 16; e++) accA[e] = bias2;   // bias in C-init

        #pragma unroll
        for (int dr = 0; dr < 3; dr++) {
            #pragma unroll
            for (int dc = 0; dc < 3; dc++) {
                const int tap = dr * 3 + dc;
                bf16x8 a0 = *(const bf16x8*)&h1s[e0a[dc] + dr * 1032];
                bf16x8 a1 = *(const bf16x8*)&h1s[e1a[dc] + dr * 1032];
                accA = __builtin_amdgcn_mfma_f32_32x32x16_bf16(a0, breg[2 * tap],     accA, 0, 0, 0);
                accB = __builtin_amdgcn_mfma_f32_32x32x16_bf16(a1, breg[2 * tap + 1], accB, 0, 0, 0);
            }
        }

        // epilogue: fold chains, add mneg (0 / -1e30), max over quad, relu
        int slg = 8 * Mt + half;
        #pragma unroll
        for (int gg = 0; gg < 4; gg++) {
            if (slg < 98) {
                f32x4 mn = *(const f32x4*)&mneg[slg * 4];
                float v0 = accA[gg * 4 + 0] + accB[gg * 4 + 0] + mn[0];
                float v1 = accA[gg * 4 + 1] + accB[gg * 4 + 1] + mn[1];
                float v2 = accA[gg * 4 + 2] + accB[gg * 4 + 2] + mn[2];
                float v3 = accA[gg * 4 + 3] + accB[gg * 4 + 3] + mn[3];
                float pm = fmaxf(fmaxf(v0, v1), fmaxf(v2, v3));
                pout[slg * 64] = (bf16)fmaxf(pm, 0.f);
            }
            slg += 2;
        }

        pj += 2; if (pj >= 14) { pj -= 14; pi += 1; }
        pi += 1;
    }
}

// ---------------------------------------------------------------------------
// fc1: bf16 MFMA split-K GEMM, BK=64 double-buffered global_load_lds.
// ks=7 slices of 1792 k. part[ks][m][n], grid (128,7). (unchanged from R10)
// ---------------------------------------------------------------------------
__global__ __launch_bounds__(256, 4)
void fc1(const bf16* __restrict__ pooled, const bf16* __restrict__ wl1t,
         float* __restrict__ part)
{
    __shared__ __attribute__((aligned(16))) bf16 As[2][32 * 64];
    __shared__ __attribute__((aligned(16))) bf16 Bs[2][128 * 64];

    const int t    = threadIdx.x;
    const int lane = t & 63;
    const int wv   = t >> 6;
    const int ml   = lane & 15;
    const int kg   = lane >> 4;
    const int wm   = wv & 1;
    const int wn   = wv >> 1;
    const int m0   = blockIdx.x * 32;
    const int ks   = blockIdx.y;
    const int k0   = ks * 1792;

    const bf16* asrc;
    {
        int c  = t;
        int sub = c >> 7, i = c & 127;
        int r  = i >> 2;
        int jq = (i & 3) ^ ((r >> 1) & 3);
        asrc = pooled + (long)(m0 + r) * 12544 + k0 + sub * 32 + jq * 8;
    }
    bf16* adst0 = &As[0][wv * 512];
    bf16* adst1 = &As[1][wv * 512];

    const bf16* bsrc[4];
    int bbase[4];
    #pragma unroll
    for (int u = 0; u < 4; u++) {
        int c  = u * 256 + t;
        int sub = c >> 9, i = c & 511;
        int r  = i >> 2;
        int jq = (i & 3) ^ ((r >> 1) & 3);
        bsrc[u]  = wl1t + (long)r * 12544 + k0 + sub * 32 + jq * 8;
        bbase[u] = (u * 256 + wv * 64) * 8;
    }

    const int am = wm * 16 + ml;
    int aoff[2], boff[4];
    #pragma unroll
    for (int s = 0; s < 2; s++)
        aoff[s] = s * 1024 + ((am * 32 + kg * 8) ^ ((am & 6) << 2));
    #pragma unroll
    for (int j = 0; j < 4; j++) {
        int n = wn * 64 + j * 16 + ml;
        boff[j] = (n * 32 + kg * 8) ^ ((n & 6) << 2);
    }

    f32x4 acc[4];
    {
        f32x4 z = {0.f, 0.f, 0.f, 0.f};
        #pragma unroll
        for (int j = 0; j < 4; j++) acc[j] = z;
    }

    load_lds16(asrc, adst0);
    #pragma unroll
    for (int u = 0; u < 4; u++) load_lds16(bsrc[u], &Bs[0][bbase[u]]);

    for (int kt = 0; kt < 28; kt++) {
        __syncthreads();
        const int cur = kt & 1;
        if (kt < 27) {
            const int kb = (kt + 1) * 64;
            load_lds16(asrc + kb, cur ? adst0 : adst1);
            #pragma unroll
            for (int u = 0; u < 4; u++)
                load_lds16(bsrc[u] + kb, &Bs[cur ^ 1][bbase[u]]);
        }
        #pragma unroll
        for (int s = 0; s < 2; s++) {
            bf16x8 af = *(const bf16x8*)&As[cur][aoff[s]];
            #pragma unroll
            for (int j = 0; j < 4; j++) {
                bf16x8 bf = *(const bf16x8*)&Bs[cur][s * 4096 + boff[j]];
                acc[j] = __builtin_amdgcn_mfma_f32_16x16x32_bf16(af, bf, acc[j], 0, 0, 0);
            }
        }
    }

    float* pp = part + ((long)ks * 4096 + m0 + wm * 16) * 128 + wn * 64;
    #pragma unroll
    for (int j = 0; j < 4; j++)
        #pragma unroll
        for (int r = 0; r < 4; r++)
            pp[(kg * 4 + r) * 128 + j * 16 + ml] = acc[j][r];
}

// ---------------------------------------------------------------------------
// fc2_lsm: one wave per image; 7-way split-K reduce + FC2 + log_softmax.
// ---------------------------------------------------------------------------
__global__ __launch_bounds__(256)
void fc2_lsm(const float* __restrict__ part, const float* __restrict__ bl1,
             const float* __restrict__ Wl2, const float* __restrict__ bl2,
             float* __restrict__ out)
{
    const int wv   = threadIdx.x >> 6;
    const int lane = threadIdx.x & 63;
    const int img  = blockIdx.x * 4 + wv;
    const float* pb = part + (long)img * 128;

    float ac[10];
    #pragma unroll
    for (int c = 0; c < 10; c++) ac[c] = 0.f;

    #pragma unroll
    for (int u = 0; u < 2; u++) {
        int n = lane + 64 * u;
        float s = bl1[n];
        #pragma unroll
        for (int k = 0; k < 7; k++) s += pb[(long)k * 4096 * 128 + n];
        float h = s > 0.f ? s : 0.f;
        #pragma unroll
        for (int c = 0; c < 10; c++) ac[c] += h * Wl2[n * 10 + c];
    }
    #pragma unroll
    for (int o = 32; o > 0; o >>= 1)
        #pragma unroll
        for (int c = 0; c < 10; c++) ac[c] += __shfl_down(ac[c], o, 64);

    if (lane == 0) {
        float lg[10], mx = -1e30f;
        #pragma unroll
        for (int c = 0; c < 10; c++) {
            lg[c] = ac[c] + bl2[c];
            mx = lg[c] > mx ? lg[c] : mx;
        }
        float se = 0.f;
        #pragma unroll
        for (int c = 0; c < 10; c++) se += __expf(lg[c] - mx);
        float ls = __logf(se);
        #pragma unroll
        for (int c = 0; c < 10; c++) out[img * 10 + c] = lg[c] - mx - ls;
    }
}

// ---------------------------------------------------------------------------
extern "C" void kernel_launch(void* const* d_in, const int* in_sizes, int n_in,
                              void* d_out, int out_size, void* d_ws, size_t ws_size,
                              hipStream_t stream) {
    const float* x   = (const float*)d_in[0];
    const float* W1  = (const float*)d_in[1];
    const float* b1  = (const float*)d_in[2];
    const float* W2  = (const float*)d_in[3];
    const float* b2  = (const float*)d_in[4];
    const float* Wl1 = (const float*)d_in[5];
    const float* bl1 = (const float*)d_in[6];
    const float* Wl2 = (const float*)d_in[7];
    const float* bl2 = (const float*)d_in[8];
    float* out = (float*)d_out;

    char* ws = (char*)d_ws;
    bf16*  w2r    = (bf16*)ws;                                   // 36,864 B
    bf16*  w1f    = (bf16*)(ws + 40960);                         //  1,024 B
    bf16*  wl1t   = (bf16*)(ws + 65536);                         // 3,211,264 B
    bf16*  pooled = (bf16*)(ws + 65536 + 4194304);               // 102,760,448 B
    float* part   = (float*)(ws + 65536 + 4194304 + 102760448);  // 14,680,064 B

    prep_w2   <<<74,             256, 0, stream>>>(W2, w2r, W1, w1f);
    prep_wl1t <<<dim3(196, 2),   256, 0, stream>>>(Wl1, wl1t);
    conv_fused<<<8192,           256, 0, stream>>>(x, b1, w2r, w1f, b2, pooled);
    fc1       <<<dim3(128, 7),   256, 0, stream>>>(pooled, wl1t, part);
    fc2_lsm   <<<1024,           256, 0, stream>>>(part, bl1, Wl2, bl2, out);
}

// Round 12
// 268.480 us; speedup vs baseline: 1.1292x; 1.1292x over previous
//
#include <hip/hip_runtime.h>
#include <math.h>

typedef __bf16 bf16;
typedef __bf16 bf16x8 __attribute__((ext_vector_type(8)));
typedef unsigned short u16;
typedef unsigned short u16x4 __attribute__((ext_vector_type(4)));
typedef unsigned short u16x8 __attribute__((ext_vector_type(8)));
typedef float f32x4 __attribute__((ext_vector_type(4)));
typedef float f32x16 __attribute__((ext_vector_type(16)));
typedef unsigned int u32x4 __attribute__((ext_vector_type(4)));

__device__ __forceinline__ void load_lds16(const void* g, void* l) {
    __builtin_amdgcn_global_load_lds(
        (const __attribute__((address_space(1))) unsigned int*)g,
        (__attribute__((address_space(3))) unsigned int*)l, 16, 0, 0);
}

// ---------------------------------------------------------------------------
// prep_w2: W2 [cout][ci][tap] f32 -> B-frag buffer for mfma_32x32x16 (conv2),
// PLUS W1 [32][9] f32 -> B-frag buffer w1f for conv1 (K=16, taps 9..15 = 0).
// ---------------------------------------------------------------------------
__global__ void prep_w2(const float* __restrict__ W2, bf16* __restrict__ w2r,
                        const float* __restrict__ W1, bf16* __restrict__ w1f) {
    int e = blockIdx.x * 256 + threadIdx.x;
    if (e < 18432) {
        int j  = e & 7;
        int l  = (e >> 3) & 63;
        int f  = e >> 9;
        int s  = f >> 1;
        int nt = f & 1;
        int tap  = s >> 1;
        int ci   = (s & 1) * 16 + (l >> 5) * 8 + j;
        int cout = nt * 32 + (l & 31);
        w2r[e] = (bf16)W2[cout * 288 + ci * 9 + tap];
    } else {
        int e2 = e - 18432;
        if (e2 < 512) {
            int j = e2 & 7;
            int l = e2 >> 3;
            int k = (l >> 5) * 8 + j;       // tap index (K)
            int n = l & 31;                 // cout
            w1f[e2] = (k < 9) ? (bf16)W1[n * 9 + k] : (bf16)0.f;
        }
    }
}

// ---------------------------------------------------------------------------
// prep_wl1t: Wl1 f32 [12544][128] -> bf16 [128][12544] with permuted K:
// wl1t[n][k'] where k' = site*64 + cout  <->  Wl1 row k = cout*196 + site.
// ---------------------------------------------------------------------------
__global__ void prep_wl1t(const float* __restrict__ Wl1, bf16* __restrict__ wl1t) {
    __shared__ float tile[32 * 129];
    const int t  = threadIdx.x;
    const int s  = blockIdx.x;      // site 0..195
    const int cg = blockIdx.y;      // cout half
    for (int e = t; e < 4096; e += 256) {
        int cl = e >> 7, n = e & 127;
        tile[cl * 129 + n] = Wl1[((long)(cg * 32 + cl) * 196 + s) * 128 + n];
    }
    __syncthreads();
    for (int e = t; e < 4096; e += 256) {
        int n = e >> 5, cl = e & 31;
        wl1t[(long)n * 12544 + s * 64 + cg * 32 + cl] = (bf16)tile[cl * 129 + n];
    }
}

// ---------------------------------------------------------------------------
// conv_fused: BOTH convs on MFMA. h1s layout [row][col*32ci], row stride 1032
// el, col swizzle ((col&6)<<2) on the ci-block; tap offsets are ds_read
// immediates. R12: mrow stored as u16 -> LDS total 53280 B <= 54613 B
// (= 160KiB/3) -> 3 blocks/CU. R11 lesson: 54784 B tipped to 2 blocks/CU and
// cost 26% wall time — keep LDS under 54613 B.
// __launch_bounds__(256,3) REQUIRED: (256,4) spills breg (R3, R6: 1.3 GB
// scratch). DO NOT raise to 4.  !! LDS fills > 256 elems: strided loops (R8).
// ---------------------------------------------------------------------------
__global__ __launch_bounds__(256, 3)
void conv_fused(const float* __restrict__ x, const float* __restrict__ b1,
                const bf16* __restrict__ w2r, const bf16* __restrict__ w1f,
                const float* __restrict__ b2, bf16* __restrict__ pooled)
{
    __shared__ __attribute__((aligned(16))) bf16  h1s[16 * 1032];   // 33024 B
    __shared__ __attribute__((aligned(16))) bf16  Aim[512 * 16];    // 16384 B
    __shared__ __attribute__((aligned(16))) u16   mrow[512];        //  1024 B
    __shared__ __attribute__((aligned(16))) float mneg[98 * 4];     //  1568 B
    __shared__ __attribute__((aligned(16))) bf16  xs[640];          //  1280 B

    const int t    = threadIdx.x;
    const int lane = t & 63;
    const int wv   = t >> 6;
    const int img  = blockIdx.x >> 1;
    const int hb   = blockIdx.x & 1;        // image half
    const int nt   = wv & 1;                // conv2 cout half
    const int wp   = wv >> 1;               // conv2 Mt parity
    const int ml31 = lane & 31;
    const int lg   = lane >> 5;

    const float* xi = x + img * 784;

    // global loads early (L2-resident; latency hides behind staging)
    bf16x8 breg[18];
    {
        const bf16x8* wp2 = (const bf16x8*)w2r;
        #pragma unroll
        for (int s = 0; s < 18; s++)
            breg[s] = wp2[(2 * s + nt) * 64 + lane];
    }
    const bf16x8 w1frag = *(const bf16x8*)&w1f[lane * 8];
    const float  b1r    = b1[ml31];
    const float  bias2  = b2[nt * 32 + ml31];

    // stage x tile (bf16): xs[j*32+c] = x[hb*14-2+j][c-1], rows 0..19 (pad)
    for (int e = t; e < 640; e += 256) {
        int j  = e >> 5;
        int c  = e & 31;
        int xr = hb * 14 - 2 + j;
        int xc = c - 1;
        float v = 0.f;
        if (xr >= 0 && xr < 28 && xc >= 0 && xc < 28) v = xi[xr * 28 + xc];
        xs[e] = (bf16)v;
    }
    __syncthreads();

    // ---- phase 1: im2col (512 pos = 16 rows x 32 cols) + masks (u16 copies)
    const u16* xu = (const u16*)xs;
    #pragma unroll
    for (int pp = 0; pp < 2; pp++) {
        int p = t + pp * 256;               // 0..511
        int r = p >> 5, c = p & 31;
        int b = r * 32 + c - 1;             // c=0 -> reads pad (masked)
        u16 v0 = xu[b],      v1 = xu[b + 1],  v2 = xu[b + 2];
        u16 v3 = xu[b + 32], v4 = xu[b + 33], v5 = xu[b + 34];
        u16 v6 = xu[b + 64], v7 = xu[b + 65], v8 = xu[b + 66];
        u16x8 t0;
        t0[0] = v0; t0[1] = v1; t0[2] = v2; t0[3] = v3;
        t0[4] = v4; t0[5] = v5; t0[6] = v6; t0[7] = v7;
        u16x8 t1;
        #pragma unroll
        for (int j = 0; j < 8; j++) t1[j] = 0;
        t1[0] = v8;
        *(u16x8*)&Aim[p * 16]     = *(u16x8*)&t0;
        *(u16x8*)&Aim[p * 16 + 8] = *(u16x8*)&t1;
        // center valid: col in [1,28] and x-center nonzero (row-validity is
        // implicit: out-of-image rows staged as 0)
        mrow[p] = (c >= 1 && c <= 28 && (v4 & 0x7fff) != 0) ? 1 : 0;
    }
    // mneg: 392 entries > 256 threads -> strided loop (R8 lesson)
    for (int e = t; e < 392; e += 256) {
        int s   = e >> 2, q = e & 3;
        int spi = s / 14, spj = s - spi * 14;
        u16 cv = xu[(2 * spi + (q >> 1) + 2) * 32 + 2 * spj + (q & 1) + 1];
        mneg[e] = ((cv & 0x7fff) != 0) ? 0.f : -1e30f;
    }
    __syncthreads();

    // ---- phase 2: conv1 via MFMA 32x32x16; 16 M-tiles, 4 per wave.
    // Writes EVERY h1s cell (mask zeroes halo cols 0,29,30,31).
    for (int Mt = wv; Mt < 16; Mt += 4) {
        int m = Mt * 32 + ml31;
        bf16x8 af = *(const bf16x8*)&Aim[m * 16 + lg * 8];
        f32x16 acc;
        #pragma unroll
        for (int e = 0; e < 16; e++) acc[e] = b1r;
        acc = __builtin_amdgcn_mfma_f32_32x32x16_bf16(af, w1frag, acc, 0, 0, 0);
        const int rowb = Mt * 1032;                  // row == Mt (p = Mt*32+off)
        #pragma unroll
        for (int run = 0; run < 4; run++) {
            int p0 = Mt * 32 + run * 8 + 4 * lg;
            u16x4 mk = *(const u16x4*)&mrow[p0];
            #pragma unroll
            for (int j = 0; j < 4; j++) {
                float s = acc[run * 4 + j];
                float o = (mk[j] != 0) ? fmaxf(s, 0.f) : 0.f;   // select: NaN-safe
                int col = run * 8 + 4 * lg + j;
                int swz = (col & 6) << 2;
                h1s[rowb + col * 32 + (ml31 ^ swz)] = (bf16)o;
            }
        }
    }
    __syncthreads();    // h1s ready

    // ---- phase 3: conv2 Mt loop (13 tiles of 32 M-rows, 98 pooled sites)
    const int half = lg;
    const int cib  = half * 8;

    int q  = ml31 & 3;
    int pj = wp * 8 + (ml31 >> 2);
    int pi = 0;
    if (pj >= 14) { pj -= 14; pi = 1; }

    bf16* pout = pooled + (long)img * 12544 + hb * 98 * 64 + nt * 32 + ml31;

    for (int Mt = wp; Mt < 13; Mt += 2) {
        int row = 2 * pi + (q >> 1);
        if (row > 13) row = 13;             // keep reads (row+2) in bounds;
                                            // affected lanes' stores guarded
        int colb = 2 * pj + (q & 1);
        int rowb = row * 1032;

        // 6 base addresses; tap row-offsets are ds_read immediates (dr*1032 el)
        int e0a[3], e1a[3];
        #pragma unroll
        for (int dc = 0; dc < 3; dc++) {
            int cc   = colb + dc;
            int swz  = (cc & 6) << 2;
            int base = rowb + cc * 32;
            e0a[dc] = base + (cib ^ swz);
            e1a[dc] = base + ((16 + cib) ^ swz);
        }

        f32x16 accA, accB = {};
        #pragma unroll
        for (int e = 0; e < 16; e++) accA[e] = bias2;   // bias in C-init

        #pragma unroll
        for (int dr = 0; dr < 3; dr++) {
            #pragma unroll
            for (int dc = 0; dc < 3; dc++) {
                const int tap = dr * 3 + dc;
                bf16x8 a0 = *(const bf16x8*)&h1s[e0a[dc] + dr * 1032];
                bf16x8 a1 = *(const bf16x8*)&h1s[e1a[dc] + dr * 1032];
                accA = __builtin_amdgcn_mfma_f32_32x32x16_bf16(a0, breg[2 * tap],     accA, 0, 0, 0);
                accB = __builtin_amdgcn_mfma_f32_32x32x16_bf16(a1, breg[2 * tap + 1], accB, 0, 0, 0);
            }
        }

        // epilogue: fold chains, add mneg (0 / -1e30), max over quad, relu
        int slg = 8 * Mt + half;
        #pragma unroll
        for (int gg = 0; gg < 4; gg++) {
            if (slg < 98) {
                f32x4 mn = *(const f32x4*)&mneg[slg * 4];
                float v0 = accA[gg * 4 + 0] + accB[gg * 4 + 0] + mn[0];
                float v1 = accA[gg * 4 + 1] + accB[gg * 4 + 1] + mn[1];
                float v2 = accA[gg * 4 + 2] + accB[gg * 4 + 2] + mn[2];
                float v3 = accA[gg * 4 + 3] + accB[gg * 4 + 3] + mn[3];
                float pm = fmaxf(fmaxf(v0, v1), fmaxf(v2, v3));
                pout[slg * 64] = (bf16)fmaxf(pm, 0.f);
            }
            slg += 2;
        }

        pj += 2; if (pj >= 14) { pj -= 14; pi += 1; }
        pi += 1;
    }
}

// ---------------------------------------------------------------------------
// fc1: bf16 MFMA split-K GEMM, BK=64 double-buffered global_load_lds.
// ks=7 slices of 1792 k. part[ks][m][n], grid (128,7). (unchanged from R10)
// ---------------------------------------------------------------------------
__global__ __launch_bounds__(256, 4)
void fc1(const bf16* __restrict__ pooled, const bf16* __restrict__ wl1t,
         float* __restrict__ part)
{
    __shared__ __attribute__((aligned(16))) bf16 As[2][32 * 64];
    __shared__ __attribute__((aligned(16))) bf16 Bs[2][128 * 64];

    const int t    = threadIdx.x;
    const int lane = t & 63;
    const int wv   = t >> 6;
    const int ml   = lane & 15;
    const int kg   = lane >> 4;
    const int wm   = wv & 1;
    const int wn   = wv >> 1;
    const int m0   = blockIdx.x * 32;
    const int ks   = blockIdx.y;
    const int k0   = ks * 1792;

    const bf16* asrc;
    {
        int c  = t;
        int sub = c >> 7, i = c & 127;
        int r  = i >> 2;
        int jq = (i & 3) ^ ((r >> 1) & 3);
        asrc = pooled + (long)(m0 + r) * 12544 + k0 + sub * 32 + jq * 8;
    }
    bf16* adst0 = &As[0][wv * 512];
    bf16* adst1 = &As[1][wv * 512];

    const bf16* bsrc[4];
    int bbase[4];
    #pragma unroll
    for (int u = 0; u < 4; u++) {
        int c  = u * 256 + t;
        int sub = c >> 9, i = c & 511;
        int r  = i >> 2;
        int jq = (i & 3) ^ ((r >> 1) & 3);
        bsrc[u]  = wl1t + (long)r * 12544 + k0 + sub * 32 + jq * 8;
        bbase[u] = (u * 256 + wv * 64) * 8;
    }

    const int am = wm * 16 + ml;
    int aoff[2], boff[4];
    #pragma unroll
    for (int s = 0; s < 2; s++)
        aoff[s] = s * 1024 + ((am * 32 + kg * 8) ^ ((am & 6) << 2));
    #pragma unroll
    for (int j = 0; j < 4; j++) {
        int n = wn * 64 + j * 16 + ml;
        boff[j] = (n * 32 + kg * 8) ^ ((n & 6) << 2);
    }

    f32x4 acc[4];
    {
        f32x4 z = {0.f, 0.f, 0.f, 0.f};
        #pragma unroll
        for (int j = 0; j < 4; j++) acc[j] = z;
    }

    load_lds16(asrc, adst0);
    #pragma unroll
    for (int u = 0; u < 4; u++) load_lds16(bsrc[u], &Bs[0][bbase[u]]);

    for (int kt = 0; kt < 28; kt++) {
        __syncthreads();
        const int cur = kt & 1;
        if (kt < 27) {
            const int kb = (kt + 1) * 64;
            load_lds16(asrc + kb, cur ? adst0 : adst1);
            #pragma unroll
            for (int u = 0; u < 4; u++)
                load_lds16(bsrc[u] + kb, &Bs[cur ^ 1][bbase[u]]);
        }
        #pragma unroll
        for (int s = 0; s < 2; s++) {
            bf16x8 af = *(const bf16x8*)&As[cur][aoff[s]];
            #pragma unroll
            for (int j = 0; j < 4; j++) {
                bf16x8 bf = *(const bf16x8*)&Bs[cur][s * 4096 + boff[j]];
                acc[j] = __builtin_amdgcn_mfma_f32_16x16x32_bf16(af, bf, acc[j], 0, 0, 0);
            }
        }
    }

    float* pp = part + ((long)ks * 4096 + m0 + wm * 16) * 128 + wn * 64;
    #pragma unroll
    for (int j = 0; j < 4; j++)
        #pragma unroll
        for (int r = 0; r < 4; r++)
            pp[(kg * 4 + r) * 128 + j * 16 + ml] = acc[j][r];
}

// ---------------------------------------------------------------------------
// fc2_lsm: one wave per image; 7-way split-K reduce + FC2 + log_softmax.
// ---------------------------------------------------------------------------
__global__ __launch_bounds__(256)
void fc2_lsm(const float* __restrict__ part, const float* __restrict__ bl1,
             const float* __restrict__ Wl2, const float* __restrict__ bl2,
             float* __restrict__ out)
{
    const int wv   = threadIdx.x >> 6;
    const int lane = threadIdx.x & 63;
    const int img  = blockIdx.x * 4 + wv;
    const float* pb = part + (long)img * 128;

    float ac[10];
    #pragma unroll
    for (int c = 0; c < 10; c++) ac[c] = 0.f;

    #pragma unroll
    for (int u = 0; u < 2; u++) {
        int n = lane + 64 * u;
        float s = bl1[n];
        #pragma unroll
        for (int k = 0; k < 7; k++) s += pb[(long)k * 4096 * 128 + n];
        float h = s > 0.f ? s : 0.f;
        #pragma unroll
        for (int c = 0; c < 10; c++) ac[c] += h * Wl2[n * 10 + c];
    }
    #pragma unroll
    for (int o = 32; o > 0; o >>= 1)
        #pragma unroll
        for (int c = 0; c < 10; c++) ac[c] += __shfl_down(ac[c], o, 64);

    if (lane == 0) {
        float lg[10], mx = -1e30f;
        #pragma unroll
        for (int c = 0; c < 10; c++) {
            lg[c] = ac[c] + bl2[c];
            mx = lg[c] > mx ? lg[c] : mx;
        }
        float se = 0.f;
        #pragma unroll
        for (int c = 0; c < 10; c++) se += __expf(lg[c] - mx);
        float ls = __logf(se);
        #pragma unroll
        for (int c = 0; c < 10; c++) out[img * 10 + c] = lg[c] - mx - ls;
    }
}

// ---------------------------------------------------------------------------
extern "C" void kernel_launch(void* const* d_in, const int* in_sizes, int n_in,
                              void* d_out, int out_size, void* d_ws, size_t ws_size,
                              hipStream_t stream) {
    const float* x   = (const float*)d_in[0];
    const float* W1  = (const float*)d_in[1];
    const float* b1  = (const float*)d_in[2];
    const float* W2  = (const float*)d_in[3];
    const float* b2  = (const float*)d_in[4];
    const float* Wl1 = (const float*)d_in[5];
    const float* bl1 = (const float*)d_in[6];
    const float* Wl2 = (const float*)d_in[7];
    const float* bl2 = (const float*)d_in[8];
    float* out = (float*)d_out;

    char* ws = (char*)d_ws;
    bf16*  w2r    = (bf16*)ws;                                   // 36,864 B
    bf16*  w1f    = (bf16*)(ws + 40960);                         //  1,024 B
    bf16*  wl1t   = (bf16*)(ws + 65536);                         // 3,211,264 B
    bf16*  pooled = (bf16*)(ws + 65536 + 4194304);               // 102,760,448 B
    float* part   = (float*)(ws + 65536 + 4194304 + 102760448);  // 14,680,064 B

    prep_w2   <<<74,             256, 0, stream>>>(W2, w2r, W1, w1f);
    prep_wl1t <<<dim3(196, 2),   256, 0, stream>>>(Wl1, wl1t);
    conv_fused<<<8192,           256, 0, stream>>>(x, b1, w2r, w1f, b2, pooled);
    fc1       <<<dim3(128, 7),   256, 0, stream>>>(pooled, wl1t, part);
    fc2_lsm   <<<1024,           256, 0, stream>>>(part, bl1, Wl2, bl2, out);
}

// Round 13
// 259.145 us; speedup vs baseline: 1.1699x; 1.0360x over previous
//
#include <hip/hip_runtime.h>
#include <math.h>

typedef __bf16 bf16;
typedef __bf16 bf16x8 __attribute__((ext_vector_type(8)));
typedef unsigned short u16;
typedef unsigned short u16x4 __attribute__((ext_vector_type(4)));
typedef unsigned short u16x8 __attribute__((ext_vector_type(8)));
typedef float f32x4 __attribute__((ext_vector_type(4)));
typedef float f32x16 __attribute__((ext_vector_type(16)));
typedef unsigned int u32x4 __attribute__((ext_vector_type(4)));

// ---------------------------------------------------------------------------
// prep_all: merged weight-prep (one launch instead of two).
// blocks [0,392): Wl1 f32 [12544][128] -> bf16 [128][12544], K permuted
//   k' = site*64+cout <-> Wl1 row k = cout*196+site.  s=b>>1, cg=b&1.
// blocks [392,466): W2 -> conv2 B-frag buffer w2r; W1 -> conv1 B-frag w1f.
// ---------------------------------------------------------------------------
__global__ void prep_all(const float* __restrict__ W2, bf16* __restrict__ w2r,
                         const float* __restrict__ W1, bf16* __restrict__ w1f,
                         const float* __restrict__ Wl1, bf16* __restrict__ wl1t) {
    __shared__ float tile[32 * 129];
    const int b = blockIdx.x;
    const int t = threadIdx.x;
    if (b < 392) {
        const int s  = b >> 1;
        const int cg = b & 1;
        for (int e = t; e < 4096; e += 256) {
            int cl = e >> 7, n = e & 127;
            tile[cl * 129 + n] = Wl1[((long)(cg * 32 + cl) * 196 + s) * 128 + n];
        }
        __syncthreads();
        for (int e = t; e < 4096; e += 256) {
            int n = e >> 5, cl = e & 31;
            wl1t[(long)n * 12544 + s * 64 + cg * 32 + cl] = (bf16)tile[cl * 129 + n];
        }
    } else {
        int e = (b - 392) * 256 + t;
        if (e < 18432) {
            int j  = e & 7;
            int l  = (e >> 3) & 63;
            int f  = e >> 9;
            int s  = f >> 1;
            int nt = f & 1;
            int tap  = s >> 1;
            int ci   = (s & 1) * 16 + (l >> 5) * 8 + j;
            int cout = nt * 32 + (l & 31);
            w2r[e] = (bf16)W2[cout * 288 + ci * 9 + tap];
        } else {
            int e2 = e - 18432;
            if (e2 < 512) {
                int j = e2 & 7;
                int l = e2 >> 3;
                int k = (l >> 5) * 8 + j;       // tap index (K)
                int n = l & 31;                 // cout
                w1f[e2] = (k < 9) ? (bf16)W1[n * 9 + k] : (bf16)0.f;
            }
        }
    }
}

// ---------------------------------------------------------------------------
// conv_fused: BOTH convs on MFMA. (FROZEN at R12 — passing, 171 us.)
// h1s layout [row][col*32ci], row stride 1032 el, col swizzle ((col&6)<<2);
// tap offsets are ds_read immediates. mrow u16 -> LDS 53280 B <= 54613 B
// (=160KiB/3) -> 3 blocks/CU (R11 lesson: 54784 B -> 2 blocks/CU, +26% wall).
// __launch_bounds__(256,3) REQUIRED: (256,4) spills breg (R3, R6: 1.3 GB
// scratch). DO NOT raise to 4.  !! LDS fills > 256 elems: strided loops (R8).
// ---------------------------------------------------------------------------
__global__ __launch_bounds__(256, 3)
void conv_fused(const float* __restrict__ x, const float* __restrict__ b1,
                const bf16* __restrict__ w2r, const bf16* __restrict__ w1f,
                const float* __restrict__ b2, bf16* __restrict__ pooled)
{
    __shared__ __attribute__((aligned(16))) bf16  h1s[16 * 1032];   // 33024 B
    __shared__ __attribute__((aligned(16))) bf16  Aim[512 * 16];    // 16384 B
    __shared__ __attribute__((aligned(16))) u16   mrow[512];        //  1024 B
    __shared__ __attribute__((aligned(16))) float mneg[98 * 4];     //  1568 B
    __shared__ __attribute__((aligned(16))) bf16  xs[640];          //  1280 B

    const int t    = threadIdx.x;
    const int lane = t & 63;
    const int wv   = t >> 6;
    const int img  = blockIdx.x >> 1;
    const int hb   = blockIdx.x & 1;        // image half
    const int nt   = wv & 1;                // conv2 cout half
    const int wp   = wv >> 1;               // conv2 Mt parity
    const int ml31 = lane & 31;
    const int lg   = lane >> 5;

    const float* xi = x + img * 784;

    // global loads early (L2-resident; latency hides behind staging)
    bf16x8 breg[18];
    {
        const bf16x8* wp2 = (const bf16x8*)w2r;
        #pragma unroll
        for (int s = 0; s < 18; s++)
            breg[s] = wp2[(2 * s + nt) * 64 + lane];
    }
    const bf16x8 w1frag = *(const bf16x8*)&w1f[lane * 8];
    const float  b1r    = b1[ml31];
    const float  bias2  = b2[nt * 32 + ml31];

    // stage x tile (bf16): xs[j*32+c] = x[hb*14-2+j][c-1], rows 0..19 (pad)
    for (int e = t; e < 640; e += 256) {
        int j  = e >> 5;
        int c  = e & 31;
        int xr = hb * 14 - 2 + j;
        int xc = c - 1;
        float v = 0.f;
        if (xr >= 0 && xr < 28 && xc >= 0 && xc < 28) v = xi[xr * 28 + xc];
        xs[e] = (bf16)v;
    }
    __syncthreads();

    // ---- phase 1: im2col (512 pos = 16 rows x 32 cols) + masks (u16 copies)
    const u16* xu = (const u16*)xs;
    #pragma unroll
    for (int pp = 0; pp < 2; pp++) {
        int p = t + pp * 256;               // 0..511
        int r = p >> 5, c = p & 31;
        int b = r * 32 + c - 1;             // c=0 -> reads pad (masked)
        u16 v0 = xu[b],      v1 = xu[b + 1],  v2 = xu[b + 2];
        u16 v3 = xu[b + 32], v4 = xu[b + 33], v5 = xu[b + 34];
        u16 v6 = xu[b + 64], v7 = xu[b + 65], v8 = xu[b + 66];
        u16x8 t0;
        t0[0] = v0; t0[1] = v1; t0[2] = v2; t0[3] = v3;
        t0[4] = v4; t0[5] = v5; t0[6] = v6; t0[7] = v7;
        u16x8 t1;
        #pragma unroll
        for (int j = 0; j < 8; j++) t1[j] = 0;
        t1[0] = v8;
        *(u16x8*)&Aim[p * 16]     = *(u16x8*)&t0;
        *(u16x8*)&Aim[p * 16 + 8] = *(u16x8*)&t1;
        mrow[p] = (c >= 1 && c <= 28 && (v4 & 0x7fff) != 0) ? 1 : 0;
    }
    // mneg: 392 entries > 256 threads -> strided loop (R8 lesson)
    for (int e = t; e < 392; e += 256) {
        int s   = e >> 2, q = e & 3;
        int spi = s / 14, spj = s - spi * 14;
        u16 cv = xu[(2 * spi + (q >> 1) + 2) * 32 + 2 * spj + (q & 1) + 1];
        mneg[e] = ((cv & 0x7fff) != 0) ? 0.f : -1e30f;
    }
    __syncthreads();

    // ---- phase 2: conv1 via MFMA 32x32x16; 16 M-tiles, 4 per wave.
    for (int Mt = wv; Mt < 16; Mt += 4) {
        int m = Mt * 32 + ml31;
        bf16x8 af = *(const bf16x8*)&Aim[m * 16 + lg * 8];
        f32x16 acc;
        #pragma unroll
        for (int e = 0; e < 16; e++) acc[e] = b1r;
        acc = __builtin_amdgcn_mfma_f32_32x32x16_bf16(af, w1frag, acc, 0, 0, 0);
        const int rowb = Mt * 1032;
        #pragma unroll
        for (int run = 0; run < 4; run++) {
            int p0 = Mt * 32 + run * 8 + 4 * lg;
            u16x4 mk = *(const u16x4*)&mrow[p0];
            #pragma unroll
            for (int j = 0; j < 4; j++) {
                float s = acc[run * 4 + j];
                float o = (mk[j] != 0) ? fmaxf(s, 0.f) : 0.f;   // select: NaN-safe
                int col = run * 8 + 4 * lg + j;
                int swz = (col & 6) << 2;
                h1s[rowb + col * 32 + (ml31 ^ swz)] = (bf16)o;
            }
        }
    }
    __syncthreads();    // h1s ready

    // ---- phase 3: conv2 Mt loop (13 tiles of 32 M-rows, 98 pooled sites)
    const int half = lg;
    const int cib  = half * 8;

    int q  = ml31 & 3;
    int pj = wp * 8 + (ml31 >> 2);
    int pi = 0;
    if (pj >= 14) { pj -= 14; pi = 1; }

    bf16* pout = pooled + (long)img * 12544 + hb * 98 * 64 + nt * 32 + ml31;

    for (int Mt = wp; Mt < 13; Mt += 2) {
        int row = 2 * pi + (q >> 1);
        if (row > 13) row = 13;             // keep reads (row+2) in bounds
        int colb = 2 * pj + (q & 1);
        int rowb = row * 1032;

        int e0a[3], e1a[3];
        #pragma unroll
        for (int dc = 0; dc < 3; dc++) {
            int cc   = colb + dc;
            int swz  = (cc & 6) << 2;
            int base = rowb + cc * 32;
            e0a[dc] = base + (cib ^ swz);
            e1a[dc] = base + ((16 + cib) ^ swz);
        }

        f32x16 accA, accB = {};
        #pragma unroll
        for (int e = 0; e < 16; e++) accA[e] = bias2;   // bias in C-init

        #pragma unroll
        for (int dr = 0; dr < 3; dr++) {
            #pragma unroll
            for (int dc = 0; dc < 3; dc++) {
                const int tap = dr * 3 + dc;
                bf16x8 a0 = *(const bf16x8*)&h1s[e0a[dc] + dr * 1032];
                bf16x8 a1 = *(const bf16x8*)&h1s[e1a[dc] + dr * 1032];
                accA = __builtin_amdgcn_mfma_f32_32x32x16_bf16(a0, breg[2 * tap],     accA, 0, 0, 0);
                accB = __builtin_amdgcn_mfma_f32_32x32x16_bf16(a1, breg[2 * tap + 1], accB, 0, 0, 0);
            }
        }

        int slg = 8 * Mt + half;
        #pragma unroll
        for (int gg = 0; gg < 4; gg++) {
            if (slg < 98) {
                f32x4 mn = *(const f32x4*)&mneg[slg * 4];
                float v0 = accA[gg * 4 + 0] + accB[gg * 4 + 0] + mn[0];
                float v1 = accA[gg * 4 + 1] + accB[gg * 4 + 1] + mn[1];
                float v2 = accA[gg * 4 + 2] + accB[gg * 4 + 2] + mn[2];
                float v3 = accA[gg * 4 + 3] + accB[gg * 4 + 3] + mn[3];
                float pm = fmaxf(fmaxf(v0, v1), fmaxf(v2, v3));
                pout[slg * 64] = (bf16)fmaxf(pm, 0.f);
            }
            slg += 2;
        }

        pj += 2; if (pj >= 14) { pj -= 14; pi += 1; }
        pi += 1;
    }
}

// ---------------------------------------------------------------------------
// fc1: bf16 MFMA split-K GEMM, BK=64, REGISTER-staged double buffer.
// R13: global_load_lds's prefetch is drained by the s_waitcnt vmcnt(0) the
// compiler emits before every s_barrier (m97 structural stall) -> each of 28
// iterations paid full HBM/L3 latency. Register staging moves the vmcnt wait
// AFTER the MFMAs: load next tile into 20 VGPRs during compute, then regs ->
// LDS (fast lgkm) before the barrier. Data layout identical to R12.
// ks=7 slices of 1792 k. grid (128,7) = 896 blocks (all co-resident at 4/CU).
// ---------------------------------------------------------------------------
__global__ __launch_bounds__(256, 4)
void fc1(const bf16* __restrict__ pooled, const bf16* __restrict__ wl1t,
         float* __restrict__ part)
{
    __shared__ __attribute__((aligned(16))) bf16 As[2][32 * 64];
    __shared__ __attribute__((aligned(16))) bf16 Bs[2][128 * 64];

    const int t    = threadIdx.x;
    const int lane = t & 63;
    const int wv   = t >> 6;
    const int ml   = lane & 15;
    const int kg   = lane >> 4;
    const int wm   = wv & 1;
    const int wn   = wv >> 1;
    const int m0   = blockIdx.x * 32;
    const int ks   = blockIdx.y;
    const int k0   = ks * 1792;

    // A: 256 chunks of 16B, 1/thread; chunk t -> As element t*8.
    // src: sub=(t>>7), i=t&127, r=i>>2, jq=(i&3)^((r>>1)&3)
    const bf16* asrc;
    {
        int sub = t >> 7, i = t & 127;
        int r  = i >> 2;
        int jq = (i & 3) ^ ((r >> 1) & 3);
        asrc = pooled + (long)(m0 + r) * 12544 + k0 + sub * 32 + jq * 8;
    }
    // B: 1024 chunks, 4/thread; chunk c=u*256+t -> Bs element c*8.
    const bf16* bsrc[4];
    #pragma unroll
    for (int u = 0; u < 4; u++) {
        int c  = u * 256 + t;
        int sub = c >> 9, i = c & 511;
        int r  = i >> 2;
        int jq = (i & 3) ^ ((r >> 1) & 3);
        bsrc[u] = wl1t + (long)r * 12544 + k0 + sub * 32 + jq * 8;
    }

    const int am = wm * 16 + ml;
    int aoff[2], boff[4];
    #pragma unroll
    for (int s = 0; s < 2; s++)
        aoff[s] = s * 1024 + ((am * 32 + kg * 8) ^ ((am & 6) << 2));
    #pragma unroll
    for (int j = 0; j < 4; j++) {
        int n = wn * 64 + j * 16 + ml;
        boff[j] = (n * 32 + kg * 8) ^ ((n & 6) << 2);
    }

    f32x4 acc[4];
    {
        f32x4 z = {0.f, 0.f, 0.f, 0.f};
        #pragma unroll
        for (int j = 0; j < 4; j++) acc[j] = z;
    }

    // prologue: tile 0 -> regs -> LDS[0]
    u32x4 ra = *(const u32x4*)asrc;
    u32x4 rb[4];
    #pragma unroll
    for (int u = 0; u < 4; u++) rb[u] = *(const u32x4*)bsrc[u];
    *(u32x4*)&As[0][t * 8] = ra;
    #pragma unroll
    for (int u = 0; u < 4; u++) *(u32x4*)&Bs[0][(u * 256 + t) * 8] = rb[u];

    for (int kt = 0; kt < 28; kt++) {
        __syncthreads();                    // buf[cur] visible; buf[nxt] free
        const int cur = kt & 1;
        if (kt < 27) {                      // prefetch kt+1 into registers
            const int kb = (kt + 1) * 64;
            ra = *(const u32x4*)(asrc + kb);
            #pragma unroll
            for (int u = 0; u < 4; u++) rb[u] = *(const u32x4*)(bsrc[u] + kb);
        }
        #pragma unroll
        for (int s = 0; s < 2; s++) {       // compute on cur (hides load latency)
            bf16x8 af = *(const bf16x8*)&As[cur][aoff[s]];
            #pragma unroll
            for (int j = 0; j < 4; j++) {
                bf16x8 bf = *(const bf16x8*)&Bs[cur][s * 4096 + boff[j]];
                acc[j] = __builtin_amdgcn_mfma_f32_16x16x32_bf16(af, bf, acc[j], 0, 0, 0);
            }
        }
        if (kt < 27) {                      // regs -> LDS[nxt] (vmcnt wait here)
            *(u32x4*)&As[cur ^ 1][t * 8] = ra;
            #pragma unroll
            for (int u = 0; u < 4; u++)
                *(u32x4*)&Bs[cur ^ 1][(u * 256 + t) * 8] = rb[u];
        }
    }

    float* pp = part + ((long)ks * 4096 + m0 + wm * 16) * 128 + wn * 64;
    #pragma unroll
    for (int j = 0; j < 4; j++)
        #pragma unroll
        for (int r = 0; r < 4; r++)
            pp[(kg * 4 + r) * 128 + j * 16 + ml] = acc[j][r];
}

// ---------------------------------------------------------------------------
// fc2_lsm: one wave per image; 7-way split-K reduce + FC2 + log_softmax.
// ---------------------------------------------------------------------------
__global__ __launch_bounds__(256)
void fc2_lsm(const float* __restrict__ part, const float* __restrict__ bl1,
             const float* __restrict__ Wl2, const float* __restrict__ bl2,
             float* __restrict__ out)
{
    const int wv   = threadIdx.x >> 6;
    const int lane = threadIdx.x & 63;
    const int img  = blockIdx.x * 4 + wv;
    const float* pb = part + (long)img * 128;

    float ac[10];
    #pragma unroll
    for (int c = 0; c < 10; c++) ac[c] = 0.f;

    #pragma unroll
    for (int u = 0; u < 2; u++) {
        int n = lane + 64 * u;
        float s = bl1[n];
        #pragma unroll
        for (int k = 0; k < 7; k++) s += pb[(long)k * 4096 * 128 + n];
        float h = s > 0.f ? s : 0.f;
        #pragma unroll
        for (int c = 0; c < 10; c++) ac[c] += h * Wl2[n * 10 + c];
    }
    #pragma unroll
    for (int o = 32; o > 0; o >>= 1)
        #pragma unroll
        for (int c = 0; c < 10; c++) ac[c] += __shfl_down(ac[c], o, 64);

    if (lane == 0) {
        float lg[10], mx = -1e30f;
        #pragma unroll
        for (int c = 0; c < 10; c++) {
            lg[c] = ac[c] + bl2[c];
            mx = lg[c] > mx ? lg[c] : mx;
        }
        float se = 0.f;
        #pragma unroll
        for (int c = 0; c < 10; c++) se += __expf(lg[c] - mx);
        float ls = __logf(se);
        #pragma unroll
        for (int c = 0; c < 10; c++) out[img * 10 + c] = lg[c] - mx - ls;
    }
}

// ---------------------------------------------------------------------------
extern "C" void kernel_launch(void* const* d_in, const int* in_sizes, int n_in,
                              void* d_out, int out_size, void* d_ws, size_t ws_size,
                              hipStream_t stream) {
    const float* x   = (const float*)d_in[0];
    const float* W1  = (const float*)d_in[1];
    const float* b1  = (const float*)d_in[2];
    const float* W2  = (const float*)d_in[3];
    const float* b2  = (const float*)d_in[4];
    const float* Wl1 = (const float*)d_in[5];
    const float* bl1 = (const float*)d_in[6];
    const float* Wl2 = (const float*)d_in[7];
    const float* bl2 = (const float*)d_in[8];
    float* out = (float*)d_out;

    char* ws = (char*)d_ws;
    bf16*  w2r    = (bf16*)ws;                                   // 36,864 B
    bf16*  w1f    = (bf16*)(ws + 40960);                         //  1,024 B
    bf16*  wl1t   = (bf16*)(ws + 65536);                         // 3,211,264 B
    bf16*  pooled = (bf16*)(ws + 65536 + 4194304);               // 102,760,448 B
    float* part   = (float*)(ws + 65536 + 4194304 + 102760448);  // 14,680,064 B

    prep_all  <<<466,            256, 0, stream>>>(W2, w2r, W1, w1f, Wl1, wl1t);
    conv_fused<<<8192,           256, 0, stream>>>(x, b1, w2r, w1f, b2, pooled);
    fc1       <<<dim3(128, 7),   256, 0, stream>>>(pooled, wl1t, part);
    fc2_lsm   <<<1024,           256, 0, stream>>>(part, bl1, Wl2, bl2, out);
}